// Round 3
// baseline (90.290 us; speedup 1.0000x reference)
//
#include <hip/hip_runtime.h>

// RoiPoolingConv: crop_and_resize (bilinear, 14x14 grid) + 2x2 max pool
// fm: (38,50,512) f32; rois: (512,5) f32 [batch, x1, y1, x2, y2]
// out[n,ph,pw,c] = max over (jy,ix in {0,1}) of bilinear sample (2ph+jy, 2pw+ix)
//
// R3: one block per (roi, pw) COLUMN. Walk the 14 y-samples with a rolling
// 2-row cache of x-interpolated values: consecutive y-samples are ~0.95 fm
// rows apart, so the common case re-x-interpolates only ONE new fm row
// (2-4 loads) and often zero. ~6.6 loads/window vs 9.6 in R2, x-interp VALU
// halved, ROI setup amortized over 7 windows. All control flow block-uniform.

#define FM_H 38
#define FM_W 50
#define NCH  512

__device__ __forceinline__ float4 lerp4(const float4 a, const float4 b, const float w) {
    const float iw = 1.0f - w;
    return make_float4(a.x * iw + b.x * w,
                       a.y * iw + b.y * w,
                       a.z * iw + b.z * w,
                       a.w * iw + b.w * w);
}

__device__ __forceinline__ float4 max4(const float4 a, const float4 b) {
    return make_float4(fmaxf(a.x, b.x), fmaxf(a.y, b.y),
                       fmaxf(a.z, b.z), fmaxf(a.w, b.w));
}

#define LD4(p) (*(const float4*)(p))

__global__ __launch_bounds__(128) void roi_pool_kernel(
    const float* __restrict__ fm,
    const float* __restrict__ rois,
    float* __restrict__ out)
{
    const int bi = blockIdx.x;          // n*7 + pw
    const int n  = bi / 7;
    const int pw = bi - n * 7;
    const int c  = threadIdx.x * 4;     // 4 channels per thread (float4)

    // ROI box (block-uniform). Combined scale: (v/IM) * (dim-1).
    const float x1 = rois[n * 5 + 1];
    const float y1 = rois[n * 5 + 2];
    const float x2 = rois[n * 5 + 3];
    const float y2 = rois[n * 5 + 4];
    const float SX = 49.0f / 800.0f;    // (W-1)/IM_W
    const float SY = 37.0f / 600.0f;    // (H-1)/IM_H

    // --- x samples: i = 2*pw + {0,1} (fixed for the whole block) ---
    int   xA0, xB0, xA1, xB1;
    float wx0, wx1;
    {
        const float t0 = (float)(2 * pw)     * (1.0f / 13.0f);
        const float t1 = (float)(2 * pw + 1) * (1.0f / 13.0f);
        const float dx = x2 - x1;
        const float xx0 = (x1 + t0 * dx) * SX;
        const float xx1 = (x1 + t1 * dx) * SX;
        const float xf0 = floorf(xx0), xf1 = floorf(xx1);
        int a0 = (int)xf0; a0 = min(max(a0, 0), FM_W - 1);
        int a1 = (int)xf1; a1 = min(max(a1, 0), FM_W - 1);
        xA0 = a0; xB0 = min(a0 + 1, FM_W - 1);
        xA1 = a1; xB1 = min(a1 + 1, FM_W - 1);
        wx0 = xx0 - xf0;                 // weights from UNclipped floor
        wx1 = xx1 - xf1;
    }
    // x-dedup case: 0 = same cell, 1 = adjacent (share corner), 2 = disjoint.
    const int xcs = (xA1 == xA0) ? 0 : ((xA1 == xB0) ? 1 : 2);

    const float* fmc = fm + c;

    // x-interpolate one fm row at both sample columns, with col dedup.
    auto interpX = [&](int row, float4& t0, float4& t1) {
        const float* bp = fmc + (size_t)row * (FM_W * NCH);
        if (xcs == 0) {
            const float4 v0 = LD4(bp + xA0 * NCH);
            const float4 v1 = LD4(bp + xB0 * NCH);
            t0 = lerp4(v0, v1, wx0);
            t1 = lerp4(v0, v1, wx1);
        } else if (xcs == 1) {
            const float4 v0 = LD4(bp + xA0 * NCH);
            const float4 v1 = LD4(bp + xB0 * NCH);   // == xA1
            const float4 v2 = LD4(bp + xB1 * NCH);
            t0 = lerp4(v0, v1, wx0);
            t1 = lerp4(v1, v2, wx1);
        } else {
            const float4 v0 = LD4(bp + xA0 * NCH);
            const float4 v1 = LD4(bp + xB0 * NCH);
            const float4 v2 = LD4(bp + xA1 * NCH);
            const float4 v3 = LD4(bp + xB1 * NCH);
            t0 = lerp4(v0, v1, wx0);
            t1 = lerp4(v2, v3, wx1);
        }
    };

    // Rolling cache: x-interp results for fm rows cacheA / cacheB.
    int cacheA = -2, cacheB = -2;
    float4 tA0, tA1, tB0, tB1;

    const float dy = y2 - y1;
    float* outp = out + ((size_t)n * 49 + pw) * NCH + c;   // + ph*7*NCH per row

    for (int ph = 0; ph < 7; ++ph) {
        float4 best = make_float4(-INFINITY, -INFINITY, -INFINITY, -INFINITY);
#pragma unroll
        for (int jy = 0; jy < 2; ++jy) {
            const int j = 2 * ph + jy;
            const float t  = (float)j * (1.0f / 13.0f);
            const float yy = (y1 + t * dy) * SY;
            const float yf = floorf(yy);
            int rA = (int)yf; rA = min(max(rA, 0), FM_H - 1);
            const int   rB = min(rA + 1, FM_H - 1);
            const float wy = yy - yf;

            // Cache update (block-uniform branches). Note rA==cacheA implies
            // rB==cacheB since both are min(+1, H-1) of equal values.
            if (rA == cacheA) {
                // full hit: nothing to do
            } else if (rA == cacheB) {
                tA0 = tB0; tA1 = tB1;                     // shift down one row
                interpX(rB, tB0, tB1);
            } else {
                interpX(rA, tA0, tA1);                    // cold / jump
                interpX(rB, tB0, tB1);
            }
            cacheA = rA; cacheB = rB;

            const float4 s0 = lerp4(tA0, tB0, wy);
            const float4 s1 = lerp4(tA1, tB1, wy);
            best = max4(best, max4(s0, s1));
        }
        *(float4*)(outp + (size_t)ph * (7 * NCH)) = best;
    }
}

extern "C" void kernel_launch(void* const* d_in, const int* in_sizes, int n_in,
                              void* d_out, int out_size, void* d_ws, size_t ws_size,
                              hipStream_t stream) {
    const float* fm   = (const float*)d_in[0];   // (1,38,50,512) f32
    const float* rois = (const float*)d_in[1];   // (512,5) f32
    float* out = (float*)d_out;                  // (1,512,7,7,512) f32

    const int N = in_sizes[1] / 5;               // 512 rois
    const int blocks = N * 7;                    // one block per (roi, pw)
    roi_pool_kernel<<<blocks, NCH / 4, 0, stream>>>(fm, rois, out);
}